// Round 12
// baseline (13543.936 us; speedup 1.0000x reference)
//
#include <hip/hip_runtime.h>
#include <hip/hip_bf16.h>

typedef _Float16 f16;
typedef _Float16 f16x8 __attribute__((ext_vector_type(8)));
typedef float f32x4 __attribute__((ext_vector_type(4)));

#define B_ 128
#define T_ 256
#define D_ 1280
#define G3_ 3840
#define C_ 100
#define TB_ 32768  /* T_*B_ */
#define NBUF 16    /* rotating h buffers */

// ---- workspace layout (bytes) ----
#define O_H16  0ull                 // f16 [NBUF][B_][D_] (5.25 MB, inside dead seqb region)
#define O_H16A 8388608ull           // diag skel h scratch
#define O_H16B 16777216ull          // diag nored h scratch
#define O_H32D 33554432ull          // diag h32 scratch
#define O_SEQB 0ull                 // f16 [TB_][D_]
#define O_WIH  83886080ull          // f16 [G3_][D_]
#define O_WHH  93716480ull          // f16 [G3_][D_]
#define O_XP   103546880ull         // f16 [T_][80][3][128][16] compact slabs
#define O_H32  355860480ull         // f32 [B_][D_]
#define O_BAR  356515840ull         // u32 counters, 3 regions x 1024 u32

// ---------------- conversion / init ----------------
__global__ void k_convert(const float* __restrict__ seq, const float* __restrict__ wih,
                          const float* __restrict__ whh, f16* __restrict__ seqb,
                          f16* __restrict__ wih16, f16* __restrict__ whh16,
                          unsigned* __restrict__ bar) {
  if (blockIdx.x == 0) {
    for (int j = threadIdx.x; j < 10240; j += 256)
      __hip_atomic_store(bar + j, 0u, __ATOMIC_RELAXED, __HIP_MEMORY_SCOPE_AGENT);
  }
  const long NSEQ = (long)TB_ * (D_ / 8);
  const long NW = (long)G3_ * (D_ / 8);
  const long total = NSEQ + 2 * NW;
  for (long i = (long)blockIdx.x * blockDim.x + threadIdx.x; i < total;
       i += (long)gridDim.x * blockDim.x) {
    const float* src;
    f16* dst;
    if (i < NSEQ) {
      long row = i / (D_ / 8), c = i % (D_ / 8);
      long t = row >> 7, b = row & 127;
      src = seq + ((b * T_ + t) * (long)D_ + c * 8);
      dst = seqb + (row * (long)D_ + c * 8);
    } else if (i < NSEQ + NW) {
      long j = i - NSEQ;
      src = wih + j * 8;
      dst = wih16 + j * 8;
    } else {
      long j = i - NSEQ - NW;
      src = whh + j * 8;
      dst = whh16 + j * 8;
    }
    float4 a = *(const float4*)src, b4 = *(const float4*)(src + 4);
    f16x8 o;
    o[0] = (f16)a.x; o[1] = (f16)a.y; o[2] = (f16)a.z; o[3] = (f16)a.w;
    o[4] = (f16)b4.x; o[5] = (f16)b4.y; o[6] = (f16)b4.z; o[7] = (f16)b4.w;
    *(f16x8*)dst = o;
  }
}

// ---------------- x_proj GEMM -> compact slab layout [t][cg][g][b][c16] ----------------
__device__ __forceinline__ void gl_lds16(const f16* g, f16* lds) {
  __builtin_amdgcn_global_load_lds((const __attribute__((address_space(1))) void*)g,
                                   (__attribute__((address_space(3))) void*)lds, 16, 0, 0);
}

__global__ __launch_bounds__(256) void k_xproj(const f16* __restrict__ A, const f16* __restrict__ Bw,
                                               const float* __restrict__ bih, f16* __restrict__ Cout) {
  __shared__ f16 Alds[128 * 32];
  __shared__ f16 Blds[128 * 32];
  int bid = blockIdx.x;
  int sb = bid / 240;
  int wi = bid % 240;
  int bm = sb * 8 + (wi & 7);
  int bn = wi >> 3;
  long brow = (long)bm * 128;
  int bcol = bn * 128;
  int tid = threadIdx.x, w = tid >> 6, l = tid & 63;
  int wm = w & 1, wn = w >> 1;

  f32x4 acc[4][4] = {};

  int sr = w * 32 + (l >> 2);
  int sc = (l & 3) * 8;
  const f16* gA = A + (brow + sr) * (long)D_ + sc;
  const f16* gB = Bw + (long)(bcol + sr) * D_ + sc;
  f16* lAw = Alds + (w * 32) * 32;
  f16* lBw = Blds + (w * 32) * 32;

  int fr = l & 15, fc = (l >> 4) * 8;

  for (int kb = 0; kb < 40; ++kb) {
    const f16* a0 = gA + kb * 32;
    const f16* b0 = gB + kb * 32;
    gl_lds16(a0, lAw);
    gl_lds16(a0 + 16 * D_, lAw + 16 * 32);
    gl_lds16(b0, lBw);
    gl_lds16(b0 + 16 * D_, lBw + 16 * 32);
    __syncthreads();
    f16x8 af[4], bf[4];
#pragma unroll
    for (int mt = 0; mt < 4; ++mt) af[mt] = *(const f16x8*)(Alds + (wm * 64 + mt * 16 + fr) * 32 + fc);
#pragma unroll
    for (int nt = 0; nt < 4; ++nt) bf[nt] = *(const f16x8*)(Blds + (wn * 64 + nt * 16 + fr) * 32 + fc);
#pragma unroll
    for (int mt = 0; mt < 4; ++mt)
#pragma unroll
      for (int nt = 0; nt < 4; ++nt)
        acc[mt][nt] = __builtin_amdgcn_mfma_f32_16x16x32_f16(af[mt], bf[nt], acc[mt][nt], 0, 0, 0);
    __syncthreads();
  }
#pragma unroll
  for (int nt = 0; nt < 4; ++nt) {
    int col = bcol + wn * 64 + nt * 16 + fr;
    int g = col / D_;
    int dcol = col - g * D_;
    int cg = dcol >> 4, c16 = dcol & 15;
    float bv = bih[col];
    f16* base = Cout + (((long)bm * 80 + cg) * 3 + g) * 2048 + c16;
#pragma unroll
    for (int mt = 0; mt < 4; ++mt) {
#pragma unroll
      for (int i = 0; i < 4; ++i) {
        int b = wm * 64 + mt * 16 + (l >> 4) * 4 + i;
        base[b * 16] = (f16)(acc[mt][nt][i] + bv);
      }
    }
  }
}

// ---------------- GRU scan (PREFIX-TRUNCATION TIMING TEMPLATE) ----------------
// PH=0: skeleton only  — stage + A-loads(sunk) + h-store(0) + syncs + barrier. REPS=5.
// PH=1: + MFMA (accs sunk), no reduce/gates. REPS=2.
// PH=2: full real scan. REPS=1.
// Structure identical to R11: 160 blocks x 512 thr, 2 rowgroups x 80 colgroups,
// 8-wave K-split (W = 15 f16x8 = 60 VGPR/wave, pinned), xproj LDS ring staged 4 ahead,
// sc1 write-through h stores, NBUF rotation + acquire fence per 16 steps,
// 16-shard x 5-arrival barrier per rowgroup.
template <int PH, int REPS>
__global__ __launch_bounds__(512, 1) void k_scan_t(const f16* __restrict__ whh16,
                                                   const f16* __restrict__ xproj,
                                                   const float* __restrict__ bhh,
                                                   f16* __restrict__ h16, float* __restrict__ h32,
                                                   unsigned* __restrict__ bar) {
  __shared__ float red[8][3][4][257];  // identical LDS footprint across variants
  __shared__ f16 ring[8][3072];
  int wg = blockIdx.x;
  int rg = wg & 1, cg = wg >> 1;
  int r0 = rg * 64, d0 = cg * 16;
  int tid = threadIdx.x, w = tid >> 6, l = tid & 63;
  int fr = l & 15, fq = l >> 4;
  int er = tid >> 4, ec = tid & 15;
  unsigned* mycnt = bar + (rg * 16 + (cg & 15)) * 32;

  const f16* wbase = whh16 + (long)(d0 + fr) * D_ + w * 160 + fq * 8;
  f16x8 wf[5][3];
#pragma unroll
  for (int j = 0; j < 5; ++j)
#pragma unroll
    for (int g = 0; g < 3; ++g) {
      wf[j][g] = *(const f16x8*)(wbase + (long)g * (D_ * D_) + j * 32);
      asm volatile("" : "+v"(wf[j][g]));
    }

  auto stage = [&](int tt) {
    if (w < 6) {
      int g = w >> 1, hh = w & 1;
      const f16* src = xproj + ((((long)tt * 80 + cg) * 3 + g) << 11) + (r0 + hh * 32) * 16 + l * 8;
      gl_lds16(src, &ring[tt & 7][(g * 2 + hh) * 512]);
    }
  };

  if ((tid & 1) == 0) {
#pragma unroll
    for (int hh = 0; hh < 2; ++hh) {
      unsigned* p = (unsigned*)(h16 + (long)(r0 + er + hh * 32) * D_ + d0 + ec);
      __hip_atomic_store(p, 0u, __ATOMIC_RELAXED, __HIP_MEMORY_SCOPE_AGENT);
    }
  }

  float bh0 = bhh[0 * D_ + d0 + ec];
  float bh1 = bhh[1 * D_ + d0 + ec];
  float bh2 = bhh[2 * D_ + d0 + ec];
  float hreg[2] = {0.f, 0.f};

  auto poll = [&](unsigned target) {
    unsigned it = 0;
    for (;;) {
      unsigned v = target;
      if (l < 16)
        v = __hip_atomic_load(bar + (rg * 16 + l) * 32, __ATOMIC_RELAXED, __HIP_MEMORY_SCOPE_AGENT);
      if (__all(v >= target)) break;
      __builtin_amdgcn_s_sleep(1);
      if (++it > 500000u) {
        if (l < 16)
          v = __hip_atomic_fetch_add(bar + (rg * 16 + l) * 32, 0u, __ATOMIC_RELAXED,
                                     __HIP_MEMORY_SCOPE_AGENT);
        if (__all(v >= target)) break;
        it = 0;
      }
    }
  };

  stage(0); stage(1); stage(2); stage(3);
  __syncthreads();
  if (tid == 0)
    __hip_atomic_fetch_add(mycnt, 1u, __ATOMIC_RELAXED, __HIP_MEMORY_SCOPE_AGENT);
  if (tid < 64) {
    poll(5u);
    if (tid == 0) __builtin_amdgcn_fence(__ATOMIC_ACQUIRE, "agent");
  }
  __syncthreads();

  const int NT = T_ * REPS;
  unsigned tgt = 10u;
  for (int t = 0; t < NT; ++t) {
    int tm = t & 255;
    stage((tm + 4) & 255);
    const f16* hc = h16 + (long)(t & (NBUF - 1)) * (B_ * D_);
    const f16* ar0 = hc + (long)(r0 + fr) * D_ + w * 160 + fq * 8;
    f32x4 acc[4][3] = {};
#pragma unroll
    for (int j = 0; j < 5; ++j) {
      f16x8 a[4];
#pragma unroll
      for (int m = 0; m < 4; ++m) a[m] = *(const f16x8*)(ar0 + (long)m * 16 * D_ + j * 32);
      if constexpr (PH == 0) {
#pragma unroll
        for (int m = 0; m < 4; ++m) asm volatile("" :: "v"(a[m]));  // keep loads live
      } else {
#pragma unroll
        for (int m = 0; m < 4; ++m) {
          acc[m][0] = __builtin_amdgcn_mfma_f32_16x16x32_f16(a[m], wf[j][0], acc[m][0], 0, 0, 0);
          acc[m][1] = __builtin_amdgcn_mfma_f32_16x16x32_f16(a[m], wf[j][1], acc[m][1], 0, 0, 0);
          acc[m][2] = __builtin_amdgcn_mfma_f32_16x16x32_f16(a[m], wf[j][2], acc[m][2], 0, 0, 0);
        }
      }
    }
    float hnew[2] = {0.f, 0.f};
    if constexpr (PH == 1) {
#pragma unroll
      for (int m = 0; m < 4; ++m)
#pragma unroll
        for (int g = 0; g < 3; ++g)
          asm volatile("" :: "v"(acc[m][g]));  // keep MFMA live; no reduce
    }
    if constexpr (PH == 2) {
#pragma unroll
      for (int m = 0; m < 4; ++m)
#pragma unroll
        for (int g = 0; g < 3; ++g)
#pragma unroll
          for (int i = 0; i < 4; ++i)
            red[w][g][m][(((fq * 4 + i) * 16) + fr) ^ (fq << 2)] = acc[m][g][i];
      __syncthreads();
      const f16* xs = ring[tm & 7];
#pragma unroll
      for (int hh = 0; hh < 2; ++hh) {
        int row = er + hh * 32;
        int m = row >> 4, r16 = row & 15;
        int pos = ((r16 * 16) + ec) ^ ((r16 >> 2) << 2);
        float s0 = 0.f, s1 = 0.f, s2 = 0.f;
#pragma unroll
        for (int ww = 0; ww < 8; ++ww) {
          s0 += red[ww][0][m][pos];
          s1 += red[ww][1][m][pos];
          s2 += red[ww][2][m][pos];
        }
        float xr = (float)xs[0 * 1024 + row * 16 + ec];
        float xz = (float)xs[1 * 1024 + row * 16 + ec];
        float xn = (float)xs[2 * 1024 + row * 16 + ec];
        float r = 1.f / (1.f + __expf(-(xr + s0 + bh0)));
        float z = 1.f / (1.f + __expf(-(xz + s1 + bh1)));
        float pn = xn + r * (s2 + bh2);
        pn = fminf(fmaxf(pn, -30.f), 30.f);
        float e2 = __expf(-2.f * pn);
        float nn = (1.f - e2) / (1.f + e2);
        hnew[hh] = (1.f - z) * nn + z * hreg[hh];
        hreg[hh] = hnew[hh];
      }
    }
    if (t == NT - 1) break;
    // h store (all PH variants: same traffic; PH<2 stores zeros)
    f16* hn = h16 + (long)((t + 1) & (NBUF - 1)) * (B_ * D_);
#pragma unroll
    for (int hh = 0; hh < 2; ++hh) {
      unsigned short bits = __builtin_bit_cast(unsigned short, (f16)hnew[hh]);
      unsigned other = (unsigned)__shfl_xor((int)bits, 1);
      if ((tid & 1) == 0) {
        unsigned val = (unsigned)bits | (other << 16);
        __hip_atomic_store((unsigned*)(hn + (long)(r0 + er + hh * 32) * D_ + d0 + ec), val,
                           __ATOMIC_RELAXED, __HIP_MEMORY_SCOPE_AGENT);
      }
    }
    __syncthreads();
    if (tid == 0)
      __hip_atomic_fetch_add(mycnt, 1u, __ATOMIC_RELAXED, __HIP_MEMORY_SCOPE_AGENT);
    if (tid < 64) poll(tgt);
    tgt += 5u;
    if (tid == 0 && (((t + 1) & (NBUF - 1)) == 0))
      __builtin_amdgcn_fence(__ATOMIC_ACQUIRE, "agent");
    __syncthreads();
  }
#pragma unroll
  for (int hh = 0; hh < 2; ++hh)
    h32[(long)(r0 + er + hh * 32) * D_ + d0 + ec] = hreg[hh];
}

// ---------------- scores: out[b][c] = sum_d h[b][d]*cand[b][c][d] (fp32) ----------------
__global__ __launch_bounds__(256) void k_scores(const float* __restrict__ h32,
                                                const float* __restrict__ cand,
                                                float* __restrict__ out) {
  int gw = blockIdx.x * 4 + (threadIdx.x >> 6);
  int l = threadIdx.x & 63;
  int b = gw / C_, c = gw % C_;
  const float* hp = h32 + (long)b * D_;
  const float* cp = cand + ((long)b * C_ + c) * D_;
  float s = 0.f;
#pragma unroll
  for (int q = 0; q < 5; ++q) {
    int d = q * 256 + l * 4;
    float4 hv = *(const float4*)(hp + d);
    float4 cv = *(const float4*)(cp + d);
    s += hv.x * cv.x + hv.y * cv.y + hv.z * cv.z + hv.w * cv.w;
  }
#pragma unroll
  for (int off = 32; off > 0; off >>= 1) s += __shfl_down(s, off);
  if (l == 0) out[(long)b * C_ + c] = s;
}

extern "C" void kernel_launch(void* const* d_in, const int* in_sizes, int n_in, void* d_out,
                              int out_size, void* d_ws, size_t ws_size, hipStream_t stream) {
  const float* seq = (const float*)d_in[0];
  const float* cand = (const float*)d_in[1];
  const float* wih = (const float*)d_in[2];
  const float* whh = (const float*)d_in[3];
  const float* bih = (const float*)d_in[4];
  const float* bhh = (const float*)d_in[5];
  char* ws = (char*)d_ws;
  f16* seqb = (f16*)(ws + O_SEQB);
  f16* wih16 = (f16*)(ws + O_WIH);
  f16* whh16 = (f16*)(ws + O_WHH);
  f16* xp = (f16*)(ws + O_XP);
  f16* h16 = (f16*)(ws + O_H16);
  f16* h16a = (f16*)(ws + O_H16A);
  f16* h16b = (f16*)(ws + O_H16B);
  float* h32 = (float*)(ws + O_H32);
  float* h32d = (float*)(ws + O_H32D);
  unsigned* bar = (unsigned*)(ws + O_BAR);

  k_convert<<<2048, 256, 0, stream>>>(seq, wih, whh, seqb, wih16, whh16, bar);
  k_xproj<<<7680, 256, 0, stream>>>(seqb, wih16, bih, xp);
  // ---- prefix-truncation diagnostics (scratch state; outputs unused) ----
  k_scan_t<0, 5><<<160, 512, 0, stream>>>(whh16, xp, bhh, h16a, h32d, bar + 1024);  // skeleton x5
  k_scan_t<1, 2><<<160, 512, 0, stream>>>(whh16, xp, bhh, h16b, h32d, bar + 2048);  // +MFMA x2
  // ---- real ----
  k_scan_t<2, 1><<<160, 512, 0, stream>>>(whh16, xp, bhh, h16, h32, bar);
  k_scores<<<3200, 256, 0, stream>>>(h32, cand, (float*)d_out);
}

// Round 13
// 2399.303 us; speedup vs baseline: 5.6449x; 5.6449x over previous
//
#include <hip/hip_runtime.h>
#include <hip/hip_bf16.h>

typedef _Float16 f16;
typedef _Float16 f16x8 __attribute__((ext_vector_type(8)));
typedef float f32x4 __attribute__((ext_vector_type(4)));

#define B_ 128
#define T_ 256
#define D_ 1280
#define G3_ 3840
#define C_ 100
#define TB_ 32768  /* T_*B_ */
#define NBUF 16    /* rotating h buffers */

// ---- workspace layout (bytes) ----
#define O_H16  0ull                 // f16 [NBUF][B_][D_] (5.25 MB, inside dead seqb region)
#define O_SEQB 0ull                 // f16 [TB_][D_]
#define O_WIH  83886080ull          // f16 [G3_][D_]
#define O_WHH  93716480ull          // f16 [G3_][D_]
#define O_XP   103546880ull         // f16 [T_][80][3][128][16] compact slabs
#define O_H32  355860480ull         // f32 [B_][D_]
#define O_BAR  356515840ull         // u32 counters

// ---------------- conversion / init ----------------
__global__ void k_convert(const float* __restrict__ seq, const float* __restrict__ wih,
                          const float* __restrict__ whh, f16* __restrict__ seqb,
                          f16* __restrict__ wih16, f16* __restrict__ whh16,
                          unsigned* __restrict__ bar) {
  if (blockIdx.x == 0) {
    for (int j = threadIdx.x; j < 10240; j += 256)
      __hip_atomic_store(bar + j, 0u, __ATOMIC_RELAXED, __HIP_MEMORY_SCOPE_AGENT);
  }
  const long NSEQ = (long)TB_ * (D_ / 8);
  const long NW = (long)G3_ * (D_ / 8);
  const long total = NSEQ + 2 * NW;
  for (long i = (long)blockIdx.x * blockDim.x + threadIdx.x; i < total;
       i += (long)gridDim.x * blockDim.x) {
    const float* src;
    f16* dst;
    if (i < NSEQ) {
      long row = i / (D_ / 8), c = i % (D_ / 8);
      long t = row >> 7, b = row & 127;
      src = seq + ((b * T_ + t) * (long)D_ + c * 8);
      dst = seqb + (row * (long)D_ + c * 8);
    } else if (i < NSEQ + NW) {
      long j = i - NSEQ;
      src = wih + j * 8;
      dst = wih16 + j * 8;
    } else {
      long j = i - NSEQ - NW;
      src = whh + j * 8;
      dst = whh16 + j * 8;
    }
    float4 a = *(const float4*)src, b4 = *(const float4*)(src + 4);
    f16x8 o;
    o[0] = (f16)a.x; o[1] = (f16)a.y; o[2] = (f16)a.z; o[3] = (f16)a.w;
    o[4] = (f16)b4.x; o[5] = (f16)b4.y; o[6] = (f16)b4.z; o[7] = (f16)b4.w;
    *(f16x8*)dst = o;
  }
}

// ---------------- x_proj GEMM -> compact slab layout [t][cg][g][b][c16] ----------------
__device__ __forceinline__ void gl_lds16(const f16* g, f16* lds) {
  __builtin_amdgcn_global_load_lds((const __attribute__((address_space(1))) void*)g,
                                   (__attribute__((address_space(3))) void*)lds, 16, 0, 0);
}

__global__ __launch_bounds__(256) void k_xproj(const f16* __restrict__ A, const f16* __restrict__ Bw,
                                               const float* __restrict__ bih, f16* __restrict__ Cout) {
  __shared__ f16 Alds[128 * 32];
  __shared__ f16 Blds[128 * 32];
  int bid = blockIdx.x;
  int sb = bid / 240;
  int wi = bid % 240;
  int bm = sb * 8 + (wi & 7);
  int bn = wi >> 3;
  long brow = (long)bm * 128;
  int bcol = bn * 128;
  int tid = threadIdx.x, w = tid >> 6, l = tid & 63;
  int wm = w & 1, wn = w >> 1;

  f32x4 acc[4][4] = {};

  int sr = w * 32 + (l >> 2);
  int sc = (l & 3) * 8;
  const f16* gA = A + (brow + sr) * (long)D_ + sc;
  const f16* gB = Bw + (long)(bcol + sr) * D_ + sc;
  f16* lAw = Alds + (w * 32) * 32;
  f16* lBw = Blds + (w * 32) * 32;

  int fr = l & 15, fc = (l >> 4) * 8;

  for (int kb = 0; kb < 40; ++kb) {
    const f16* a0 = gA + kb * 32;
    const f16* b0 = gB + kb * 32;
    gl_lds16(a0, lAw);
    gl_lds16(a0 + 16 * D_, lAw + 16 * 32);
    gl_lds16(b0, lBw);
    gl_lds16(b0 + 16 * D_, lBw + 16 * 32);
    __syncthreads();
    f16x8 af[4], bf[4];
#pragma unroll
    for (int mt = 0; mt < 4; ++mt) af[mt] = *(const f16x8*)(Alds + (wm * 64 + mt * 16 + fr) * 32 + fc);
#pragma unroll
    for (int nt = 0; nt < 4; ++nt) bf[nt] = *(const f16x8*)(Blds + (wn * 64 + nt * 16 + fr) * 32 + fc);
#pragma unroll
    for (int mt = 0; mt < 4; ++mt)
#pragma unroll
      for (int nt = 0; nt < 4; ++nt)
        acc[mt][nt] = __builtin_amdgcn_mfma_f32_16x16x32_f16(af[mt], bf[nt], acc[mt][nt], 0, 0, 0);
    __syncthreads();
  }
#pragma unroll
  for (int nt = 0; nt < 4; ++nt) {
    int col = bcol + wn * 64 + nt * 16 + fr;
    int g = col / D_;
    int dcol = col - g * D_;
    int cg = dcol >> 4, c16 = dcol & 15;
    float bv = bih[col];
    f16* base = Cout + (((long)bm * 80 + cg) * 3 + g) * 2048 + c16;
#pragma unroll
    for (int mt = 0; mt < 4; ++mt) {
#pragma unroll
      for (int i = 0; i < 4; ++i) {
        int b = wm * 64 + mt * 16 + (l >> 4) * 4 + i;
        base[b * 16] = (f16)(acc[mt][nt][i] + bv);
      }
    }
  }
}

// ---------------- GRU scan: 160 blocks x 512 threads ----------------
// KEY CHANGE vs R11/R12: NO vmcnt(0) anywhere in the step loop.
//  - xproj: per-thread register prefetch issued 2 steps ahead (two named sets, 2x unroll).
//  - end-of-step drain: sched_barrier-pinned [stores][6 prefetch loads][s_waitcnt vmcnt(6)]
//    -> waits the OLDEST ops (the h-stores, m135 semantics), prefetch stays in flight
//    across the raw s_barrier (T3/T4 counted-vmcnt pattern).
//  - mid-step red barrier: lgkmcnt(0) + raw s_barrier (LDS-only).
// Rest identical to R11: K-split-8 (W = 15 f16x8 = 60 VGPR/wave pinned), sc1 h stores,
// NBUF rotation + acquire fence per 16 steps, 16-shard x 5-arrival barrier per rowgroup.
__global__ __launch_bounds__(512, 1) void k_scan(const f16* __restrict__ whh16,
                                                 const f16* __restrict__ xproj,
                                                 const float* __restrict__ bhh,
                                                 f16* __restrict__ h16, float* __restrict__ h32,
                                                 unsigned* __restrict__ bar) {
  __shared__ float red[8][3][4][257];
  int wg = blockIdx.x;
  int rg = wg & 1, cg = wg >> 1;
  int r0 = rg * 64, d0 = cg * 16;
  int tid = threadIdx.x, w = tid >> 6, l = tid & 63;
  int fr = l & 15, fq = l >> 4;
  int er = tid >> 4, ec = tid & 15;
  unsigned* mycnt = bar + (rg * 16 + (cg & 15)) * 32;

  const f16* wbase = whh16 + (long)(d0 + fr) * D_ + w * 160 + fq * 8;
  f16x8 wf[5][3];
#pragma unroll
  for (int j = 0; j < 5; ++j)
#pragma unroll
    for (int g = 0; g < 3; ++g) {
      wf[j][g] = *(const f16x8*)(wbase + (long)g * (D_ * D_) + j * 32);
      asm volatile("" : "+v"(wf[j][g]));
    }

  if ((tid & 1) == 0) {
#pragma unroll
    for (int hh = 0; hh < 2; ++hh) {
      unsigned* p = (unsigned*)(h16 + (long)(r0 + er + hh * 32) * D_ + d0 + ec);
      __hip_atomic_store(p, 0u, __ATOMIC_RELAXED, __HIP_MEMORY_SCOPE_AGENT);
    }
  }

  float bh0 = bhh[0 * D_ + d0 + ec];
  float bh1 = bhh[1 * D_ + d0 + ec];
  float bh2 = bhh[2 * D_ + d0 + ec];
  float hreg[2] = {0.f, 0.f};

  auto poll = [&](unsigned target) {
    unsigned it = 0;
    for (;;) {
      unsigned v = target;
      if (l < 16)
        v = __hip_atomic_load(bar + (rg * 16 + l) * 32, __ATOMIC_RELAXED, __HIP_MEMORY_SCOPE_AGENT);
      if (__all(v >= target)) break;
      __builtin_amdgcn_s_sleep(1);
      if (++it > 500000u) {
        if (l < 16)
          v = __hip_atomic_fetch_add(bar + (rg * 16 + l) * 32, 0u, __ATOMIC_RELAXED,
                                     __HIP_MEMORY_SCOPE_AGENT);
        if (__all(v >= target)) break;
        it = 0;
      }
    }
  };

  // xproj element addresses for this thread (2 rows x 3 gates)
  const f16* xbase = xproj + ((long)cg * 3) * 2048 + ec;
#define XADDR(tt, hh, g) (xbase + ((long)(tt)*80 * 3 + (g)) * 2048 + (r0 + er + (hh)*32) * 16)

  f16 xgA[2][3], xgB[2][3];
#pragma unroll
  for (int hh = 0; hh < 2; ++hh)
#pragma unroll
    for (int g = 0; g < 3; ++g) {
      xgA[hh][g] = *XADDR(0, hh, g);
      xgB[hh][g] = *XADDR(1, hh, g);
    }

  // initial barrier + cross-replay cache scrub
  __syncthreads();
  if (tid == 0)
    __hip_atomic_fetch_add(mycnt, 1u, __ATOMIC_RELAXED, __HIP_MEMORY_SCOPE_AGENT);
  if (tid < 64) {
    poll(5u);
    if (tid == 0) __builtin_amdgcn_fence(__ATOMIC_ACQUIRE, "agent");
  }
  __syncthreads();

  unsigned tgt = 10u;

  auto step = [&](int t, f16 (&xg)[2][3]) {
    const f16* hc = h16 + (long)(t & (NBUF - 1)) * (B_ * D_);
    const f16* ar0 = hc + (long)(r0 + fr) * D_ + w * 160 + fq * 8;
    f32x4 acc[4][3] = {};
#pragma unroll
    for (int j = 0; j < 5; ++j) {
      f16x8 a[4];
#pragma unroll
      for (int m = 0; m < 4; ++m) a[m] = *(const f16x8*)(ar0 + (long)m * 16 * D_ + j * 32);
#pragma unroll
      for (int m = 0; m < 4; ++m) {
        acc[m][0] = __builtin_amdgcn_mfma_f32_16x16x32_f16(a[m], wf[j][0], acc[m][0], 0, 0, 0);
        acc[m][1] = __builtin_amdgcn_mfma_f32_16x16x32_f16(a[m], wf[j][1], acc[m][1], 0, 0, 0);
        acc[m][2] = __builtin_amdgcn_mfma_f32_16x16x32_f16(a[m], wf[j][2], acc[m][2], 0, 0, 0);
      }
    }
#pragma unroll
    for (int m = 0; m < 4; ++m)
#pragma unroll
      for (int g = 0; g < 3; ++g)
#pragma unroll
        for (int i = 0; i < 4; ++i)
          red[w][g][m][(((fq * 4 + i) * 16) + fr) ^ (fq << 2)] = acc[m][g][i];
    // mid-step barrier: LDS-only drain (no vmcnt!)
    asm volatile("s_waitcnt lgkmcnt(0)" ::: "memory");
    __builtin_amdgcn_sched_barrier(0);
    __builtin_amdgcn_s_barrier();
    asm volatile("" ::: "memory");

    float hnew[2];
#pragma unroll
    for (int hh = 0; hh < 2; ++hh) {
      int row = er + hh * 32;
      int m = row >> 4, r16 = row & 15;
      int pos = ((r16 * 16) + ec) ^ ((r16 >> 2) << 2);
      float s0 = 0.f, s1 = 0.f, s2 = 0.f;
#pragma unroll
      for (int ww = 0; ww < 8; ++ww) {
        s0 += red[ww][0][m][pos];
        s1 += red[ww][1][m][pos];
        s2 += red[ww][2][m][pos];
      }
      float xr = (float)xg[hh][0], xz = (float)xg[hh][1], xn = (float)xg[hh][2];
      float r = 1.f / (1.f + __expf(-(xr + s0 + bh0)));
      float z = 1.f / (1.f + __expf(-(xz + s1 + bh1)));
      float pn = xn + r * (s2 + bh2);
      pn = fminf(fmaxf(pn, -30.f), 30.f);
      float e2 = __expf(-2.f * pn);
      float nn = (1.f - e2) / (1.f + e2);
      hnew[hh] = (1.f - z) * nn + z * hreg[hh];
      hreg[hh] = hnew[hh];
    }
    if (t == T_ - 1) return;  // last h stays in hreg

    // ---- pinned cluster: [2 stores][6 prefetch loads][vmcnt(6)] ----
    f16* hn = h16 + (long)((t + 1) & (NBUF - 1)) * (B_ * D_);
#pragma unroll
    for (int hh = 0; hh < 2; ++hh) {
      unsigned short bits = __builtin_bit_cast(unsigned short, (f16)hnew[hh]);
      unsigned other = (unsigned)__shfl_xor((int)bits, 1);
      if ((tid & 1) == 0) {
        unsigned val = (unsigned)bits | (other << 16);
        __hip_atomic_store((unsigned*)(hn + (long)(r0 + er + hh * 32) * D_ + d0 + ec), val,
                           __ATOMIC_RELAXED, __HIP_MEMORY_SCOPE_AGENT);
      }
    }
    __builtin_amdgcn_sched_barrier(0);
    {
      int tp = (t + 2 < T_) ? t + 2 : t;  // clamp: harmless reload near tail
#pragma unroll
      for (int hh = 0; hh < 2; ++hh)
#pragma unroll
        for (int g = 0; g < 3; ++g)
          xg[hh][g] = *XADDR(tp, hh, g);  // lands by use at step t+2
    }
    __builtin_amdgcn_sched_barrier(0);
    asm volatile("s_waitcnt vmcnt(6)" ::: "memory");  // oldest-first: waits the 2 stores
    __builtin_amdgcn_sched_barrier(0);
    __builtin_amdgcn_s_barrier();  // raw: prefetch loads stay in flight

    if (tid == 0)
      __hip_atomic_fetch_add(mycnt, 1u, __ATOMIC_RELAXED, __HIP_MEMORY_SCOPE_AGENT);
    if (tid < 64) {
      poll(tgt);
      if (tid == 0 && (((t + 1) & (NBUF - 1)) == 0))
        __builtin_amdgcn_fence(__ATOMIC_ACQUIRE, "agent");  // periodic stale-line scrub
    }
    tgt += 5u;
    __builtin_amdgcn_s_barrier();
    asm volatile("" ::: "memory");
  };

  for (int t2 = 0; t2 < T_; t2 += 2) {
    step(t2, xgA);
    step(t2 + 1, xgB);
  }
#pragma unroll
  for (int hh = 0; hh < 2; ++hh)
    h32[(long)(r0 + er + hh * 32) * D_ + d0 + ec] = hreg[hh];
#undef XADDR
}

// ---------------- scores: out[b][c] = sum_d h[b][d]*cand[b][c][d] (fp32) ----------------
__global__ __launch_bounds__(256) void k_scores(const float* __restrict__ h32,
                                                const float* __restrict__ cand,
                                                float* __restrict__ out) {
  int gw = blockIdx.x * 4 + (threadIdx.x >> 6);
  int l = threadIdx.x & 63;
  int b = gw / C_, c = gw % C_;
  const float* hp = h32 + (long)b * D_;
  const float* cp = cand + ((long)b * C_ + c) * D_;
  float s = 0.f;
#pragma unroll
  for (int q = 0; q < 5; ++q) {
    int d = q * 256 + l * 4;
    float4 hv = *(const float4*)(hp + d);
    float4 cv = *(const float4*)(cp + d);
    s += hv.x * cv.x + hv.y * cv.y + hv.z * cv.z + hv.w * cv.w;
  }
#pragma unroll
  for (int off = 32; off > 0; off >>= 1) s += __shfl_down(s, off);
  if (l == 0) out[(long)b * C_ + c] = s;
}

extern "C" void kernel_launch(void* const* d_in, const int* in_sizes, int n_in, void* d_out,
                              int out_size, void* d_ws, size_t ws_size, hipStream_t stream) {
  const float* seq = (const float*)d_in[0];
  const float* cand = (const float*)d_in[1];
  const float* wih = (const float*)d_in[2];
  const float* whh = (const float*)d_in[3];
  const float* bih = (const float*)d_in[4];
  const float* bhh = (const float*)d_in[5];
  char* ws = (char*)d_ws;
  f16* seqb = (f16*)(ws + O_SEQB);
  f16* wih16 = (f16*)(ws + O_WIH);
  f16* whh16 = (f16*)(ws + O_WHH);
  f16* xp = (f16*)(ws + O_XP);
  f16* h16 = (f16*)(ws + O_H16);
  float* h32 = (float*)(ws + O_H32);
  unsigned* bar = (unsigned*)(ws + O_BAR);

  k_convert<<<2048, 256, 0, stream>>>(seq, wih, whh, seqb, wih16, whh16, bar);
  k_xproj<<<7680, 256, 0, stream>>>(seqb, wih16, bih, xp);
  k_scan<<<160, 512, 0, stream>>>(whh16, xp, bhh, h16, h32, bar);
  k_scores<<<3200, 256, 0, stream>>>(h32, cand, (float*)d_out);
}